// Round 10
// baseline (492.576 us; speedup 1.0000x reference)
//
#include <hip/hip_runtime.h>
#include <math.h>

typedef _Float16 h16;
typedef h16  h16x8 __attribute__((ext_vector_type(8)));
typedef h16  h16x4 __attribute__((ext_vector_type(4)));
typedef float f32x4 __attribute__((ext_vector_type(4)));

// ---------------- workspace layout (bytes) ----------------
// MH/ML : fp16 split of M [32 b][1024 j][256 d] (x2 zero-padded to 256)
// UHt/ULt: fp16 split of (U^T * 4) [2 h][256 d][256 c]   (*4 = 1/16 * 64 prescale)
// rmax_all/rmax_hi: [64 hb][1024] f32 ; pcm: [64 hb][16 rb][1024] f32
// m0key: ordered-int encoding of raw global min of head-0 K
#define MH_OFF   ((size_t)0)
#define ML_OFF   (MH_OFF + 16777216)
#define UHT_OFF  (ML_OFF + 16777216)
#define ULT_OFF  (UHT_OFF + 262144)
#define RMA_OFF  (ULT_OFF + 262144)
#define RMH_OFF  (RMA_OFF + 262144)
#define PCM_OFF  (RMH_OFF + 262144)
#define M0_OFF   (PCM_OFF + 4194304)

// Fully-converged Newton solve of y^3/3 + y = x (nonsat_activation limit).
// Strictly monotone -> commutes with max/min (applied post-reduction).
__device__ __forceinline__ float nonsat(float x) {
    float y = x;
#pragma unroll
    for (int i = 0; i < 24; ++i) {
        float y2 = y * y;
        y = fmaf(0.66666667f * y, y2, x) / (y2 + 1.0f);
    }
    return y;
}

// monotone float->int key (signed-int compare order == float order, no NaNs)
__device__ __forceinline__ int fkey(float f) {
    const int i = __float_as_int(f);
    return (i >= 0) ? i : (i ^ 0x7fffffff);
}
__device__ __forceinline__ float funkey(int k) {
    return __int_as_float((k >= 0) ? k : (k ^ 0x7fffffff));
}

// ---------------------------------------------------------------------------
// k_prep: fp16 hi/lo split of virtual M (x2 zero-padded) and of U^T*4.
// Also zeroes d_out (k_fin accumulates with atomicAdd) and inits m0key.
// ---------------------------------------------------------------------------
__global__ void k_prep(const float* __restrict__ x1, const float* __restrict__ x2,
                       const float* __restrict__ U, h16* __restrict__ MH,
                       h16* __restrict__ ML, h16* __restrict__ UHt,
                       h16* __restrict__ ULt, int* __restrict__ m0key,
                       float* __restrict__ out) {
    const int gid = blockIdx.x * 256 + threadIdx.x;
    if (blockIdx.x < 8192) {
        const int g  = gid;              // (b, j, d4): 32*1024*64 groups
        const int d4 = (g & 63) * 4;
        const int j  = (g >> 6) & 1023;
        const int b  = g >> 16;
        float v[4];
        if (j < 512) {
            const float4 p = *(const float4*)(x1 + ((size_t)(b * 512 + j) * 256 + d4));
            v[0] = p.x; v[1] = p.y; v[2] = p.z; v[3] = p.w;
        } else if (d4 < 192) {           // 192 % 4 == 0: all four in-range
            const float4 p = *(const float4*)(x2 +
                (size_t)(b * 512 + (j - 512)) * 192 + d4);
            v[0] = p.x; v[1] = p.y; v[2] = p.z; v[3] = p.w;
        } else {
            v[0] = v[1] = v[2] = v[3] = 0.0f;
        }
        h16x4 hh, ll;
#pragma unroll
        for (int k = 0; k < 4; ++k) {
            const h16 hi = (h16)v[k];
            hh[k] = hi;
            ll[k] = (h16)(v[k] - (float)hi);
        }
        const size_t o = (size_t)g * 4;
        *(h16x4*)&MH[o] = hh;
        *(h16x4*)&ML[o] = ll;
    } else if (blockIdx.x < 8320) {
        const int g  = gid - 8192 * 256; // U^T: 2*256*64 groups
        const int c4 = (g & 63) * 4;
        const int d  = (g >> 6) & 255;
        const int h  = g >> 14;
        h16x4 hh, ll;
#pragma unroll
        for (int k = 0; k < 4; ++k) {
            const float v = U[((size_t)h * 256 + c4 + k) * 256 + d] * 4.0f;
            const h16 hi = (h16)v;
            hh[k] = hi;
            ll[k] = (h16)(v - (float)hi);
        }
        const size_t o = ((size_t)h * 256 + d) * 256 + c4;
        *(h16x4*)&UHt[o] = hh;
        *(h16x4*)&ULt[o] = ll;
    } else {
        const int z = gid - 8320 * 256;  // 32768 output floats to zero
        out[z] = 0.0f;
        if (z == 0) *m0key = 0x7fffffff; // +max key
    }
}

// ---------------------------------------------------------------------------
// k_main: R4 structure (64-row blocks, acc[4][8], 2 waves/SIMD — best
// measured per-wave config) + TERM-SPLIT PASSES in Phase B: per j-sweep,
// pass 1 runs all 8 kc touching ONLY MH (aH*bH + aL*bH), pass 2 runs all
// 8 kc touching ONLY ML (aH*bL). Math-identical (order-free accumulation);
// halves the instantaneous per-XCD L2 working set (R4 interleaved hi+lo =
// 4 MB for the 2 co-resident batches = exactly L2 capacity -> thrash to L3
// at ~600 cyc, matching the measured ~650-cyc/kc stall). Phase stagger
// removed (R8: slightly negative). XCD-affine swizzle keeps MH/ML[b]
// L2-resident. On-the-fly reductions; true K = K' * 2^-6.
// ---------------------------------------------------------------------------
__global__ __launch_bounds__(256, 2)
void k_main(const h16* __restrict__ MH, const h16* __restrict__ ML,
            const h16* __restrict__ UHt, const h16* __restrict__ ULt,
            float* __restrict__ rmax_all, float* __restrict__ rmax_hi,
            float* __restrict__ pcm, int* __restrict__ m0key) {
    __shared__ __align__(16) h16 sP[2][64 * 256];  // P hi/lo, XOR-swizzled, 64 KB
    __shared__ float red[512 + 4];

    // XCD-affine swizzle (round-robin blk%8 -> XCD; bijective either way)
    const int n    = blockIdx.x;       // 1024
    const int x    = n & 7;            // presumed XCD
    const int s    = n >> 3;           // 0..127 slot on this XCD
    const int b    = x + 8 * (s >> 5); // 4 batches per XCD, 32-slot runs
    const int h    = (s >> 4) & 1;
    const int rblk = s & 15;
    const int hb   = h * 32 + b;
    const int r0   = rblk * 64;
    const int t    = threadIdx.x;
    const int w    = t >> 6;           // wave 0..3
    const int l    = t & 63;
    const int q    = l >> 4;           // quad -> A/B k-offset q*8 ; C row q*4+reg
    const int ln   = l & 15;           // A/B row ; C col

    // ---------------- Phase A ----------------
    {
        f32x4 acc[4][4];
        const f32x4 z4 = {0.f, 0.f, 0.f, 0.f};
#pragma unroll
        for (int i = 0; i < 4; ++i)
#pragma unroll
            for (int j = 0; j < 4; ++j) acc[i][j] = z4;

        for (int kc = 0; kc < 8; ++kc) {
            const int c0 = kc * 32;
            h16x8 aH[4], aL[4], bH[4], bL[4];
#pragma unroll
            for (int ti = 0; ti < 4; ++ti) {
                const size_t off =
                    (size_t)(b * 1024 + r0 + ti * 16 + ln) * 256 + c0 + q * 8;
                aH[ti] = *(const h16x8*)&MH[off];
                aL[ti] = *(const h16x8*)&ML[off];
            }
#pragma unroll
            for (int tj = 0; tj < 4; ++tj) {
                const size_t off =
                    (size_t)(h * 256 + w * 64 + tj * 16 + ln) * 256 + c0 + q * 8;
                bH[tj] = *(const h16x8*)&UHt[off];
                bL[tj] = *(const h16x8*)&ULt[off];
            }
#pragma unroll
            for (int ti = 0; ti < 4; ++ti)
#pragma unroll
                for (int tj = 0; tj < 4; ++tj)
                    acc[ti][tj] = __builtin_amdgcn_mfma_f32_16x16x32_f16(
                        aH[ti], bH[tj], acc[ti][tj], 0, 0, 0);
#pragma unroll
            for (int ti = 0; ti < 4; ++ti)
#pragma unroll
                for (int tj = 0; tj < 4; ++tj)
                    acc[ti][tj] = __builtin_amdgcn_mfma_f32_16x16x32_f16(
                        aL[ti], bH[tj], acc[ti][tj], 0, 0, 0);
#pragma unroll
            for (int ti = 0; ti < 4; ++ti)
#pragma unroll
                for (int tj = 0; tj < 4; ++tj)
                    acc[ti][tj] = __builtin_amdgcn_mfma_f32_16x16x32_f16(
                        aH[ti], bL[tj], acc[ti][tj], 0, 0, 0);
        }
        // split-store P' into sP, granule-swizzled: gran' = gran ^ (r&7)
#pragma unroll
        for (int ti = 0; ti < 4; ++ti)
#pragma unroll
            for (int tj = 0; tj < 4; ++tj)
#pragma unroll
                for (int reg = 0; reg < 4; ++reg) {
                    const int r = ti * 16 + q * 4 + reg;   // C/D: row=q*4+reg
                    const int d = w * 64 + tj * 16 + ln;   //      col=ln
                    const float v = acc[ti][tj][reg];
                    const h16 hi = (h16)v;
                    const h16 lo = (h16)(v - (float)hi);
                    const int off = r * 256 + (((d >> 3) ^ (r & 7)) << 3) + (d & 7);
                    sP[0][off] = hi;
                    sP[1][off] = lo;
                }
    }
    __syncthreads();

    // ---------------- Phase B (term-split passes) ----------------
    float gmin = INFINITY;

    for (int jt = 0; jt < 2; ++jt) {
        const int jbase = jt * 512 + w * 128;
        f32x4 acc[4][8];
        const f32x4 z4 = {0.f, 0.f, 0.f, 0.f};
#pragma unroll
        for (int i = 0; i < 4; ++i)
#pragma unroll
            for (int j = 0; j < 8; ++j) acc[i][j] = z4;

        // ---- pass 1: MH-only (terms PH*MH + PL*MH) ----
        for (int kc = 0; kc < 8; ++kc) {
            const int d0 = kc * 32;
            h16x8 aH[4], aL[4], bb[8];
#pragma unroll
            for (int tj = 0; tj < 8; ++tj)
                bb[tj] = *(const h16x8*)&MH[
                    (size_t)(b * 1024 + jbase + tj * 16 + ln) * 256 + d0 + q * 8];
#pragma unroll
            for (int ti = 0; ti < 4; ++ti) {
                const int r = ti * 16 + ln;
                const int g = (kc * 4 + q) ^ (r & 7);
                aH[ti] = *(const h16x8*)&sP[0][r * 256 + g * 8];
                aL[ti] = *(const h16x8*)&sP[1][r * 256 + g * 8];
            }
#pragma unroll
            for (int tj = 0; tj < 8; ++tj)
#pragma unroll
                for (int ti = 0; ti < 4; ++ti)
                    acc[ti][tj] = __builtin_amdgcn_mfma_f32_16x16x32_f16(
                        aH[ti], bb[tj], acc[ti][tj], 0, 0, 0);
#pragma unroll
            for (int tj = 0; tj < 8; ++tj)
#pragma unroll
                for (int ti = 0; ti < 4; ++ti)
                    acc[ti][tj] = __builtin_amdgcn_mfma_f32_16x16x32_f16(
                        aL[ti], bb[tj], acc[ti][tj], 0, 0, 0);
        }
        // ---- pass 2: ML-only (term PH*ML) ----
        for (int kc = 0; kc < 8; ++kc) {
            const int d0 = kc * 32;
            h16x8 aH[4], bb[8];
#pragma unroll
            for (int tj = 0; tj < 8; ++tj)
                bb[tj] = *(const h16x8*)&ML[
                    (size_t)(b * 1024 + jbase + tj * 16 + ln) * 256 + d0 + q * 8];
#pragma unroll
            for (int ti = 0; ti < 4; ++ti) {
                const int r = ti * 16 + ln;
                const int g = (kc * 4 + q) ^ (r & 7);
                aH[ti] = *(const h16x8*)&sP[0][r * 256 + g * 8];
            }
#pragma unroll
            for (int tj = 0; tj < 8; ++tj)
#pragma unroll
                for (int ti = 0; ti < 4; ++ti)
                    acc[ti][tj] = __builtin_amdgcn_mfma_f32_16x16x32_f16(
                        aH[ti], bb[tj], acc[ti][tj], 0, 0, 0);
        }

        // rowmax for this jt -> red[(jt*4+w)*64 + row] (lane ln==0 writes)
#pragma unroll
        for (int ti = 0; ti < 4; ++ti)
#pragma unroll
            for (int reg = 0; reg < 4; ++reg) {
                float m = acc[ti][0][reg];
#pragma unroll
                for (int tj = 1; tj < 8; ++tj) m = fmaxf(m, acc[ti][tj][reg]);
                m = fmaxf(m, __shfl_xor(m, 1));
                m = fmaxf(m, __shfl_xor(m, 2));
                m = fmaxf(m, __shfl_xor(m, 4));
                m = fmaxf(m, __shfl_xor(m, 8));
                if (ln == 0)
                    red[(jt * 4 + w) * 64 + ti * 16 + q * 4 + reg] = m;
            }
        // colmax over this block's 64 rows -> pcm (quads combined via shfl)
#pragma unroll
        for (int tj = 0; tj < 8; ++tj) {
            float m = -INFINITY;
#pragma unroll
            for (int ti = 0; ti < 4; ++ti)
#pragma unroll
                for (int reg = 0; reg < 4; ++reg) m = fmaxf(m, acc[ti][tj][reg]);
            m = fmaxf(m, __shfl_xor(m, 16));
            m = fmaxf(m, __shfl_xor(m, 32));
            if (q == 0)
                pcm[(size_t)(hb * 16 + rblk) * 1024 + jbase + tj * 16 + ln] =
                    m * 0.015625f;
        }
        // raw min
#pragma unroll
        for (int ti = 0; ti < 4; ++ti)
#pragma unroll
            for (int tj = 0; tj < 8; ++tj)
#pragma unroll
                for (int reg = 0; reg < 4; ++reg)
                    gmin = fminf(gmin, acc[ti][tj][reg]);
    }

#pragma unroll
    for (int off = 1; off < 64; off <<= 1) gmin = fminf(gmin, __shfl_xor(gmin, off));
    if (l == 0) red[512 + w] = gmin;
    __syncthreads();

    if (t < 64) {
        float a = -INFINITY, hh = -INFINITY;
#pragma unroll
        for (int w2 = 0; w2 < 4; ++w2) {
            a  = fmaxf(a,  red[w2 * 64 + t]);          // jt0
            const float v1 = red[(4 + w2) * 64 + t];   // jt1 (j >= 512)
            a  = fmaxf(a, v1);
            hh = fmaxf(hh, v1);
        }
        rmax_all[(size_t)hb * 1024 + r0 + t] = a  * 0.015625f;
        rmax_hi [(size_t)hb * 1024 + r0 + t] = hh * 0.015625f;
    }
    if (t == 0 && hb < 32) {   // head 0 only feeds mask_add
        const float g4 = fminf(fminf(red[512], red[513]),
                               fminf(red[514], red[515])) * 0.015625f;
        atomicMin(m0key, fkey(g4));
    }
}

// ---------------------------------------------------------------------------
// k_fin: fused alpha (activation post-reduction) + softmax + chunked pooling.
// blk = hb*4 + seg*2 + chunk; 256 blocks x 256 thr; atomicAdd into zeroed out.
// ---------------------------------------------------------------------------
__global__ __launch_bounds__(256)
void k_fin(const float* __restrict__ rmax_all, const float* __restrict__ rmax_hi,
           const float* __restrict__ pcm, const int* __restrict__ m0key,
           const float* __restrict__ x1, const float* __restrict__ x2,
           float* __restrict__ out) {
    __shared__ float wv[512];
    __shared__ float sm[4], ss[4];
    const int blk   = blockIdx.x;
    const int chunk = blk & 1;
    const int seg   = (blk >> 1) & 1;
    const int hb    = blk >> 2;
    const int b     = hb & 31;
    const int t     = threadIdx.x;
    const float m0  = funkey(*m0key);

    float a2[2];
#pragma unroll
    for (int half = 0; half < 2; ++half) {
        const int i = seg * 512 + half * 256 + t;
        float rraw;
        if (seg == 0) rraw = fmaxf(m0, rmax_hi[(size_t)hb * 1024 + i]);
        else          rraw = rmax_all[(size_t)hb * 1024 + i];
        float call = -INFINITY, chi = -INFINITY;
#pragma unroll
        for (int rb = 0; rb < 16; ++rb) {
            const float v = pcm[(size_t)(hb * 16 + rb) * 1024 + i];
            call = fmaxf(call, v);
            if (rb >= 8) chi = fmaxf(chi, v);   // rows >= 512
        }
        const float craw = (seg == 0) ? fmaxf(m0, chi) : call;
        a2[half] = nonsat(rraw) + nonsat(craw);
    }
    const float a0 = a2[0], a1 = a2[1];

    float m = fmaxf(a0, a1);
#pragma unroll
    for (int off = 1; off < 64; off <<= 1) m = fmaxf(m, __shfl_xor(m, off));
    if ((t & 63) == 0) sm[t >> 6] = m;
    __syncthreads();
    const float amax = fmaxf(fmaxf(sm[0], sm[1]), fmaxf(sm[2], sm[3]));

    const float e0 = __expf(a0 - amax), e1 = __expf(a1 - amax);
    wv[t] = e0; wv[t + 256] = e1;
    float s = e0 + e1;
#pragma unroll
    for (int off = 1; off < 64; off <<= 1) s += __shfl_xor(s, off);
    if ((t & 63) == 0) ss[t >> 6] = s;
    __syncthreads();
    const float inv = 1.0f / (ss[0] + ss[1] + ss[2] + ss[3]);

    const int lo = chunk * 256;
    float acc = 0.0f;
    if (seg == 0) {
        const float* xp = x1 + ((size_t)b * 512 + lo) * 256 + t;
#pragma unroll 4
        for (int l = 0; l < 256; ++l)
            acc = fmaf(wv[lo + l], xp[(size_t)l * 256], acc);
        atomicAdd(&out[(hb * 2 + seg) * 256 + t], acc * inv);
    } else if (t < 192) {
        const float* xp = x2 + ((size_t)b * 512 + lo) * 192 + t;
#pragma unroll 4
        for (int l = 0; l < 256; ++l)
            acc = fmaf(wv[lo + l], xp[(size_t)l * 192], acc);
        atomicAdd(&out[(hb * 2 + seg) * 256 + t], acc * inv);
    } // padded channels >=192 of seg1 stay exactly 0 from k_prep zeroing
}

extern "C" void kernel_launch(void* const* d_in, const int* in_sizes, int n_in,
                              void* d_out, int out_size, void* d_ws, size_t ws_size,
                              hipStream_t stream) {
    const float* x1 = (const float*)d_in[0];
    const float* x2 = (const float*)d_in[1];
    const float* U  = (const float*)d_in[2];
    float* out = (float*)d_out;
    char* wsb  = (char*)d_ws;

    h16*   MHp  = (h16*)(wsb + MH_OFF);
    h16*   MLp  = (h16*)(wsb + ML_OFF);
    h16*   UHt  = (h16*)(wsb + UHT_OFF);
    h16*   ULt  = (h16*)(wsb + ULT_OFF);
    float* rma  = (float*)(wsb + RMA_OFF);
    float* rmh  = (float*)(wsb + RMH_OFF);
    float* pcm  = (float*)(wsb + PCM_OFF);
    int*   m0k  = (int*)(wsb + M0_OFF);

    hipLaunchKernelGGL(k_prep, dim3(8448), dim3(256), 0, stream, x1, x2, U,
                       MHp, MLp, UHt, ULt, m0k, out);
    hipLaunchKernelGGL(k_main, dim3(1024), dim3(256), 0, stream, MHp, MLp,
                       UHt, ULt, rma, rmh, pcm, m0k);
    hipLaunchKernelGGL(k_fin,  dim3(256),  dim3(256), 0, stream, rma, rmh,
                       pcm, m0k, x1, x2, out);
}

// Round 11
// 280.018 us; speedup vs baseline: 1.7591x; 1.7591x over previous
//
#include <hip/hip_runtime.h>
#include <math.h>

typedef _Float16 h16;
typedef h16  h16x8 __attribute__((ext_vector_type(8)));
typedef h16  h16x4 __attribute__((ext_vector_type(4)));
typedef float f32x4 __attribute__((ext_vector_type(4)));

// ---------------- workspace layout (bytes) ----------------
// MH/ML : fp16 split of M [32 b][1024 j][256 d] (x2 zero-padded to 256)
// UHt/ULt: fp16 split of (U^T * 4) [2 h][256 d][256 c]   (*4 = 1/16 * 64 prescale)
// rmax_all/rmax_hi: [64 hb][1024] f32 ; pcm: [64 hb][16 rb][1024] f32
// m0key: ordered-int encoding of raw global min of head-0 K
#define MH_OFF   ((size_t)0)
#define ML_OFF   (MH_OFF + 16777216)
#define UHT_OFF  (ML_OFF + 16777216)
#define ULT_OFF  (UHT_OFF + 262144)
#define RMA_OFF  (ULT_OFF + 262144)
#define RMH_OFF  (RMA_OFF + 262144)
#define PCM_OFF  (RMH_OFF + 262144)
#define M0_OFF   (PCM_OFF + 4194304)

// Fully-converged Newton solve of y^3/3 + y = x (nonsat_activation limit).
// Strictly monotone -> commutes with max/min (applied post-reduction).
__device__ __forceinline__ float nonsat(float x) {
    float y = x;
#pragma unroll
    for (int i = 0; i < 24; ++i) {
        float y2 = y * y;
        y = fmaf(0.66666667f * y, y2, x) / (y2 + 1.0f);
    }
    return y;
}

// monotone float->int key (signed-int compare order == float order, no NaNs)
__device__ __forceinline__ int fkey(float f) {
    const int i = __float_as_int(f);
    return (i >= 0) ? i : (i ^ 0x7fffffff);
}
__device__ __forceinline__ float funkey(int k) {
    return __int_as_float((k >= 0) ? k : (k ^ 0x7fffffff));
}

// ---------------------------------------------------------------------------
// k_prep: fp16 hi/lo split of virtual M (x2 zero-padded) and of U^T*4.
// Also zeroes d_out (k_fin accumulates with atomicAdd) and inits m0key.
// ---------------------------------------------------------------------------
__global__ void k_prep(const float* __restrict__ x1, const float* __restrict__ x2,
                       const float* __restrict__ U, h16* __restrict__ MH,
                       h16* __restrict__ ML, h16* __restrict__ UHt,
                       h16* __restrict__ ULt, int* __restrict__ m0key,
                       float* __restrict__ out) {
    const int gid = blockIdx.x * 256 + threadIdx.x;
    if (blockIdx.x < 8192) {
        const int g  = gid;              // (b, j, d4): 32*1024*64 groups
        const int d4 = (g & 63) * 4;
        const int j  = (g >> 6) & 1023;
        const int b  = g >> 16;
        float v[4];
        if (j < 512) {
            const float4 p = *(const float4*)(x1 + ((size_t)(b * 512 + j) * 256 + d4));
            v[0] = p.x; v[1] = p.y; v[2] = p.z; v[3] = p.w;
        } else if (d4 < 192) {           // 192 % 4 == 0: all four in-range
            const float4 p = *(const float4*)(x2 +
                (size_t)(b * 512 + (j - 512)) * 192 + d4);
            v[0] = p.x; v[1] = p.y; v[2] = p.z; v[3] = p.w;
        } else {
            v[0] = v[1] = v[2] = v[3] = 0.0f;
        }
        h16x4 hh, ll;
#pragma unroll
        for (int k = 0; k < 4; ++k) {
            const h16 hi = (h16)v[k];
            hh[k] = hi;
            ll[k] = (h16)(v[k] - (float)hi);
        }
        const size_t o = (size_t)g * 4;
        *(h16x4*)&MH[o] = hh;
        *(h16x4*)&ML[o] = ll;
    } else if (blockIdx.x < 8320) {
        const int g  = gid - 8192 * 256; // U^T: 2*256*64 groups
        const int c4 = (g & 63) * 4;
        const int d  = (g >> 6) & 255;
        const int h  = g >> 14;
        h16x4 hh, ll;
#pragma unroll
        for (int k = 0; k < 4; ++k) {
            const float v = U[((size_t)h * 256 + c4 + k) * 256 + d] * 4.0f;
            const h16 hi = (h16)v;
            hh[k] = hi;
            ll[k] = (h16)(v - (float)hi);
        }
        const size_t o = ((size_t)h * 256 + d) * 256 + c4;
        *(h16x4*)&UHt[o] = hh;
        *(h16x4*)&ULt[o] = ll;
    } else {
        const int z = gid - 8320 * 256;  // 32768 output floats to zero
        out[z] = 0.0f;
        if (z == 0) *m0key = 0x7fffffff; // +max key
    }
}

// ---------------------------------------------------------------------------
// k_main: the measured-optimal configuration (R4): 64-row blocks, acc[4][8],
// 2 waves/SIMD, natural loop order (R8 stagger removed: it cost +17 us).
// Phase A: P'[64][256] = M @ (U*4) via 3-term fp16-split MFMA, fragments
// direct from global -> XOR-swizzled LDS. Phase B: K' = P'.M^T; A-frags from
// LDS, B-frags direct from global (L2-resident via XCD-affine swizzle).
// Session ledger: all non-spilling variants pin MfmaUtil at ~26% — the
// unified VGPR/AGPR file conserves (waves x reuse x acc-size); deeper
// pipelines (R9/R10) and higher occupancy (R5/R7) both cost more than they
// buy. On-the-fly reductions; true K = K' * 2^-6.
// ---------------------------------------------------------------------------
__global__ __launch_bounds__(256, 2)
void k_main(const h16* __restrict__ MH, const h16* __restrict__ ML,
            const h16* __restrict__ UHt, const h16* __restrict__ ULt,
            float* __restrict__ rmax_all, float* __restrict__ rmax_hi,
            float* __restrict__ pcm, int* __restrict__ m0key) {
    __shared__ __align__(16) h16 sP[2][64 * 256];  // P hi/lo, XOR-swizzled, 64 KB
    __shared__ float red[512 + 4];

    // XCD-affine swizzle (round-robin blk%8 -> XCD; bijective either way)
    const int n    = blockIdx.x;       // 1024
    const int x    = n & 7;            // presumed XCD
    const int s    = n >> 3;           // 0..127 slot on this XCD
    const int b    = x + 8 * (s >> 5); // 4 batches per XCD
    const int h    = (s >> 4) & 1;
    const int rblk = s & 15;
    const int hb   = h * 32 + b;
    const int r0   = rblk * 64;
    const int t    = threadIdx.x;
    const int w    = t >> 6;           // wave 0..3
    const int l    = t & 63;
    const int q    = l >> 4;           // quad -> A/B k-offset q*8 ; C row q*4+reg
    const int ln   = l & 15;           // A/B row ; C col

    // ---------------- Phase A ----------------
    {
        f32x4 acc[4][4];
        const f32x4 z4 = {0.f, 0.f, 0.f, 0.f};
#pragma unroll
        for (int i = 0; i < 4; ++i)
#pragma unroll
            for (int j = 0; j < 4; ++j) acc[i][j] = z4;

        for (int kc = 0; kc < 8; ++kc) {
            const int c0 = kc * 32;
            h16x8 aH[4], aL[4], bH[4], bL[4];
#pragma unroll
            for (int ti = 0; ti < 4; ++ti) {
                const size_t off =
                    (size_t)(b * 1024 + r0 + ti * 16 + ln) * 256 + c0 + q * 8;
                aH[ti] = *(const h16x8*)&MH[off];
                aL[ti] = *(const h16x8*)&ML[off];
            }
#pragma unroll
            for (int tj = 0; tj < 4; ++tj) {
                const size_t off =
                    (size_t)(h * 256 + w * 64 + tj * 16 + ln) * 256 + c0 + q * 8;
                bH[tj] = *(const h16x8*)&UHt[off];
                bL[tj] = *(const h16x8*)&ULt[off];
            }
#pragma unroll
            for (int ti = 0; ti < 4; ++ti)
#pragma unroll
                for (int tj = 0; tj < 4; ++tj)
                    acc[ti][tj] = __builtin_amdgcn_mfma_f32_16x16x32_f16(
                        aH[ti], bH[tj], acc[ti][tj], 0, 0, 0);
#pragma unroll
            for (int ti = 0; ti < 4; ++ti)
#pragma unroll
                for (int tj = 0; tj < 4; ++tj)
                    acc[ti][tj] = __builtin_amdgcn_mfma_f32_16x16x32_f16(
                        aL[ti], bH[tj], acc[ti][tj], 0, 0, 0);
#pragma unroll
            for (int ti = 0; ti < 4; ++ti)
#pragma unroll
                for (int tj = 0; tj < 4; ++tj)
                    acc[ti][tj] = __builtin_amdgcn_mfma_f32_16x16x32_f16(
                        aH[ti], bL[tj], acc[ti][tj], 0, 0, 0);
        }
        // split-store P' into sP, granule-swizzled: gran' = gran ^ (r&7)
#pragma unroll
        for (int ti = 0; ti < 4; ++ti)
#pragma unroll
            for (int tj = 0; tj < 4; ++tj)
#pragma unroll
                for (int reg = 0; reg < 4; ++reg) {
                    const int r = ti * 16 + q * 4 + reg;   // C/D: row=q*4+reg
                    const int d = w * 64 + tj * 16 + ln;   //      col=ln
                    const float v = acc[ti][tj][reg];
                    const h16 hi = (h16)v;
                    const h16 lo = (h16)(v - (float)hi);
                    const int off = r * 256 + (((d >> 3) ^ (r & 7)) << 3) + (d & 7);
                    sP[0][off] = hi;
                    sP[1][off] = lo;
                }
    }
    __syncthreads();

    // ---------------- Phase B ----------------
    float gmin = INFINITY;

    for (int jt = 0; jt < 2; ++jt) {
        const int jbase = jt * 512 + w * 128;
        f32x4 acc[4][8];
        const f32x4 z4 = {0.f, 0.f, 0.f, 0.f};
#pragma unroll
        for (int i = 0; i < 4; ++i)
#pragma unroll
            for (int j = 0; j < 8; ++j) acc[i][j] = z4;

        for (int kc = 0; kc < 8; ++kc) {
            const int d0 = kc * 32;
            h16x8 aH[4], aL[4], bb[8];
#pragma unroll
            for (int ti = 0; ti < 4; ++ti) {
                const int r = ti * 16 + ln;
                const int g = (kc * 4 + q) ^ (r & 7);
                aH[ti] = *(const h16x8*)&sP[0][r * 256 + g * 8];
                aL[ti] = *(const h16x8*)&sP[1][r * 256 + g * 8];
            }
#pragma unroll
            for (int tj = 0; tj < 8; ++tj)
                bb[tj] = *(const h16x8*)&MH[
                    (size_t)(b * 1024 + jbase + tj * 16 + ln) * 256 + d0 + q * 8];
#pragma unroll
            for (int tj = 0; tj < 8; ++tj)
#pragma unroll
                for (int ti = 0; ti < 4; ++ti)
                    acc[ti][tj] = __builtin_amdgcn_mfma_f32_16x16x32_f16(
                        aH[ti], bb[tj], acc[ti][tj], 0, 0, 0);
#pragma unroll
            for (int tj = 0; tj < 8; ++tj)
#pragma unroll
                for (int ti = 0; ti < 4; ++ti)
                    acc[ti][tj] = __builtin_amdgcn_mfma_f32_16x16x32_f16(
                        aL[ti], bb[tj], acc[ti][tj], 0, 0, 0);
#pragma unroll
            for (int tj = 0; tj < 8; ++tj)
                bb[tj] = *(const h16x8*)&ML[
                    (size_t)(b * 1024 + jbase + tj * 16 + ln) * 256 + d0 + q * 8];
#pragma unroll
            for (int tj = 0; tj < 8; ++tj)
#pragma unroll
                for (int ti = 0; ti < 4; ++ti)
                    acc[ti][tj] = __builtin_amdgcn_mfma_f32_16x16x32_f16(
                        aH[ti], bb[tj], acc[ti][tj], 0, 0, 0);
        }

        // rowmax for this jt -> red[(jt*4+w)*64 + row] (lane ln==0 writes)
#pragma unroll
        for (int ti = 0; ti < 4; ++ti)
#pragma unroll
            for (int reg = 0; reg < 4; ++reg) {
                float m = acc[ti][0][reg];
#pragma unroll
                for (int tj = 1; tj < 8; ++tj) m = fmaxf(m, acc[ti][tj][reg]);
                m = fmaxf(m, __shfl_xor(m, 1));
                m = fmaxf(m, __shfl_xor(m, 2));
                m = fmaxf(m, __shfl_xor(m, 4));
                m = fmaxf(m, __shfl_xor(m, 8));
                if (ln == 0)
                    red[(jt * 4 + w) * 64 + ti * 16 + q * 4 + reg] = m;
            }
        // colmax over this block's 64 rows -> pcm (quads combined via shfl)
#pragma unroll
        for (int tj = 0; tj < 8; ++tj) {
            float m = -INFINITY;
#pragma unroll
            for (int ti = 0; ti < 4; ++ti)
#pragma unroll
                for (int reg = 0; reg < 4; ++reg) m = fmaxf(m, acc[ti][tj][reg]);
            m = fmaxf(m, __shfl_xor(m, 16));
            m = fmaxf(m, __shfl_xor(m, 32));
            if (q == 0)
                pcm[(size_t)(hb * 16 + rblk) * 1024 + jbase + tj * 16 + ln] =
                    m * 0.015625f;
        }
        // raw min
#pragma unroll
        for (int ti = 0; ti < 4; ++ti)
#pragma unroll
            for (int tj = 0; tj < 8; ++tj)
#pragma unroll
                for (int reg = 0; reg < 4; ++reg)
                    gmin = fminf(gmin, acc[ti][tj][reg]);
    }

#pragma unroll
    for (int off = 1; off < 64; off <<= 1) gmin = fminf(gmin, __shfl_xor(gmin, off));
    if (l == 0) red[512 + w] = gmin;
    __syncthreads();

    if (t < 64) {
        float a = -INFINITY, hh = -INFINITY;
#pragma unroll
        for (int w2 = 0; w2 < 4; ++w2) {
            a  = fmaxf(a,  red[w2 * 64 + t]);          // jt0
            const float v1 = red[(4 + w2) * 64 + t];   // jt1 (j >= 512)
            a  = fmaxf(a, v1);
            hh = fmaxf(hh, v1);
        }
        rmax_all[(size_t)hb * 1024 + r0 + t] = a  * 0.015625f;
        rmax_hi [(size_t)hb * 1024 + r0 + t] = hh * 0.015625f;
    }
    if (t == 0 && hb < 32) {   // head 0 only feeds mask_add
        const float g4 = fminf(fminf(red[512], red[513]),
                               fminf(red[514], red[515])) * 0.015625f;
        atomicMin(m0key, fkey(g4));
    }
}

// ---------------------------------------------------------------------------
// k_fin: fused alpha (activation post-reduction) + softmax + chunked pooling.
// blk = hb*4 + seg*2 + chunk; 256 blocks x 256 thr; atomicAdd into zeroed out.
// ---------------------------------------------------------------------------
__global__ __launch_bounds__(256)
void k_fin(const float* __restrict__ rmax_all, const float* __restrict__ rmax_hi,
           const float* __restrict__ pcm, const int* __restrict__ m0key,
           const float* __restrict__ x1, const float* __restrict__ x2,
           float* __restrict__ out) {
    __shared__ float wv[512];
    __shared__ float sm[4], ss[4];
    const int blk   = blockIdx.x;
    const int chunk = blk & 1;
    const int seg   = (blk >> 1) & 1;
    const int hb    = blk >> 2;
    const int b     = hb & 31;
    const int t     = threadIdx.x;
    const float m0  = funkey(*m0key);

    float a2[2];
#pragma unroll
    for (int half = 0; half < 2; ++half) {
        const int i = seg * 512 + half * 256 + t;
        float rraw;
        if (seg == 0) rraw = fmaxf(m0, rmax_hi[(size_t)hb * 1024 + i]);
        else          rraw = rmax_all[(size_t)hb * 1024 + i];
        float call = -INFINITY, chi = -INFINITY;
#pragma unroll
        for (int rb = 0; rb < 16; ++rb) {
            const float v = pcm[(size_t)(hb * 16 + rb) * 1024 + i];
            call = fmaxf(call, v);
            if (rb >= 8) chi = fmaxf(chi, v);   // rows >= 512
        }
        const float craw = (seg == 0) ? fmaxf(m0, chi) : call;
        a2[half] = nonsat(rraw) + nonsat(craw);
    }
    const float a0 = a2[0], a1 = a2[1];

    float m = fmaxf(a0, a1);
#pragma unroll
    for (int off = 1; off < 64; off <<= 1) m = fmaxf(m, __shfl_xor(m, off));
    if ((t & 63) == 0) sm[t >> 6] = m;
    __syncthreads();
    const float amax = fmaxf(fmaxf(sm[0], sm[1]), fmaxf(sm[2], sm[3]));

    const float e0 = __expf(a0 - amax), e1 = __expf(a1 - amax);
    wv[t] = e0; wv[t + 256] = e1;
    float s = e0 + e1;
#pragma unroll
    for (int off = 1; off < 64; off <<= 1) s += __shfl_xor(s, off);
    if ((t & 63) == 0) ss[t >> 6] = s;
    __syncthreads();
    const float inv = 1.0f / (ss[0] + ss[1] + ss[2] + ss[3]);

    const int lo = chunk * 256;
    float acc = 0.0f;
    if (seg == 0) {
        const float* xp = x1 + ((size_t)b * 512 + lo) * 256 + t;
#pragma unroll 4
        for (int l = 0; l < 256; ++l)
            acc = fmaf(wv[lo + l], xp[(size_t)l * 256], acc);
        atomicAdd(&out[(hb * 2 + seg) * 256 + t], acc * inv);
    } else if (t < 192) {
        const float* xp = x2 + ((size_t)b * 512 + lo) * 192 + t;
#pragma unroll 4
        for (int l = 0; l < 256; ++l)
            acc = fmaf(wv[lo + l], xp[(size_t)l * 192], acc);
        atomicAdd(&out[(hb * 2 + seg) * 256 + t], acc * inv);
    } // padded channels >=192 of seg1 stay exactly 0 from k_prep zeroing
}

extern "C" void kernel_launch(void* const* d_in, const int* in_sizes, int n_in,
                              void* d_out, int out_size, void* d_ws, size_t ws_size,
                              hipStream_t stream) {
    const float* x1 = (const float*)d_in[0];
    const float* x2 = (const float*)d_in[1];
    const float* U  = (const float*)d_in[2];
    float* out = (float*)d_out;
    char* wsb  = (char*)d_ws;

    h16*   MHp  = (h16*)(wsb + MH_OFF);
    h16*   MLp  = (h16*)(wsb + ML_OFF);
    h16*   UHt  = (h16*)(wsb + UHT_OFF);
    h16*   ULt  = (h16*)(wsb + ULT_OFF);
    float* rma  = (float*)(wsb + RMA_OFF);
    float* rmh  = (float*)(wsb + RMH_OFF);
    float* pcm  = (float*)(wsb + PCM_OFF);
    int*   m0k  = (int*)(wsb + M0_OFF);

    hipLaunchKernelGGL(k_prep, dim3(8448), dim3(256), 0, stream, x1, x2, U,
                       MHp, MLp, UHt, ULt, m0k, out);
    hipLaunchKernelGGL(k_main, dim3(1024), dim3(256), 0, stream, MHp, MLp,
                       UHt, ULt, rma, rmh, pcm, m0k);
    hipLaunchKernelGGL(k_fin,  dim3(256),  dim3(256), 0, stream, rma, rmh,
                       pcm, m0k, x1, x2, out);
}